// Round 13
// baseline (881.346 us; speedup 1.0000x reference)
//
#include <hip/hip_runtime.h>
#include <hip/hip_bf16.h>

// ---------------------------------------------------------------------------
// GCN 4-layer forward on MI355X.
//   - R6: single-pass SLOTTED CSR build (one device atomic per (bin,tile)).
//   - R5/R7: float4 gathers, 8-edge unroll.
//   - R10/R11: LDS bank law: dense float4 @16B*tid stride and stride AP%8==1
//     staging are free; transposed scalar staging (stride==4 mod 32) is 8-way.
//   - R12: mega-fusion (agg+GEMM1+GEMM2 in one kernel; h1/agg1/h2 never HBM).
//   - R13: k_fused1 W-CHUNKING. R12 counters: fused1 = 92us, occ 28% (49.6KB
//     LDS -> 3 blocks/CU) — gather phase starved of waves. W streamed in 8KB
//     chunks inside the k-loop => LDS 24.9KB -> 6 blocks/CU (75% wave occ).
//   - pool: wave segmented scan on sorted gid (R1: contended atomics 152us).
// ---------------------------------------------------------------------------

#define TILE 4096   // edges per build tile (256 threads x 16)
#define SLOT 8192   // per-bin slot capacity (bin = 512 nodes, mean ~4080 edges)

// --- build pass 1: tile->LDS, histogram, reserve slot space, scatter -------
__global__ __launch_bounds__(256) void k_buildbins(
        const int* __restrict__ src, const int* __restrict__ dst, int E, int NBIN,
        int* __restrict__ cntD, int* __restrict__ cntS,
        int* __restrict__ bucketD, unsigned short* __restrict__ bucketS) {
    __shared__ int ssrc[TILE];
    __shared__ int sdst[TILE];
    __shared__ int hD[256], hS[256], bD[256], bS[256];
    int t = threadIdx.x;
    hD[t] = 0; hS[t] = 0;
    __syncthreads();
    int base = blockIdx.x * TILE;
    int lim = min(TILE, E - base);
#pragma unroll
    for (int k = 0; k < TILE / 256; k++) {
        int i = k * 256 + t;
        if (i < lim) {
            int d = dst[base + i], sv = src[base + i];
            sdst[i] = d; ssrc[i] = sv;
            atomicAdd(&hD[d >> 9], 1);
            atomicAdd(&hS[sv >> 9], 1);
        }
    }
    __syncthreads();
    if (t < NBIN) {
        bD[t] = (hD[t] > 0) ? atomicAdd(&cntD[t], hD[t]) : 0;
        bS[t] = (hS[t] > 0) ? atomicAdd(&cntS[t], hS[t]) : 0;
        hD[t] = 0; hS[t] = 0;
    }
    __syncthreads();
#pragma unroll
    for (int k = 0; k < TILE / 256; k++) {
        int i = k * 256 + t;
        if (i < lim) {
            int d = sdst[i], sv = ssrc[i];
            int binD = d >> 9, binS = sv >> 9;
            int pD = atomicAdd(&hD[binD], 1) + bD[binD];
            bucketD[binD * SLOT + pD] = (sv << 9) | (d & 511);
            int pS = atomicAdd(&hS[binS], 1) + bS[binS];
            bucketS[binS * SLOT + pS] = (unsigned short)(sv & 511);
        }
    }
}

// --- build pass 2: per-src-bucket LDS count -> norm_out --------------------
__global__ __launch_bounds__(256) void k_degout(const unsigned short* __restrict__ bucketS,
                                                const int* __restrict__ cntS,
                                                int N, float* __restrict__ norm_out) {
    __shared__ int cnt[512];
    int t = threadIdx.x;
    cnt[t] = 0; cnt[t + 256] = 0;
    __syncthreads();
    int bin = blockIdx.x;
    int b0 = bin * SLOT, cn = cntS[bin];
    for (int j = t; j < cn; j += 256) atomicAdd(&cnt[bucketS[b0 + j]], 1);
    __syncthreads();
    int base = bin << 9;
    for (int l = t; l < 512; l += 256) {
        int g = base + l;
        if (g < N) norm_out[g] = rsqrtf(fmaxf((float)cnt[l], 1.0f));
    }
}

// --- build pass 3: per-dst-bucket count+scan -> rowBE/norm_in, place edges -
__global__ __launch_bounds__(256) void k_build(const int* __restrict__ bucketD,
                                               const int* __restrict__ cntDg,
                                               const float* __restrict__ norm_out,
                                               int N, int2* __restrict__ rowBE,
                                               float* __restrict__ norm_in,
                                               int2* __restrict__ edges) {
    __shared__ int cnt[512], sc[512];
    int t = threadIdx.x;
    cnt[t] = 0; cnt[t + 256] = 0;
    __syncthreads();
    int bin = blockIdx.x;
    int b0 = bin * SLOT, cn = cntDg[bin];
    for (int j = t; j < cn; j += 256) atomicAdd(&cnt[bucketD[b0 + j] & 511], 1);
    __syncthreads();
    sc[t] = cnt[t]; sc[t + 256] = cnt[t + 256];
    __syncthreads();
    for (int off = 1; off < 512; off <<= 1) {
        int v0 = (t >= off) ? sc[t - off] : 0;
        int i1 = t + 256;
        int v1 = sc[i1 - off];   // i1 >= 256 >= off always
        __syncthreads();
        sc[t] += v0; sc[i1] += v1;
        __syncthreads();
    }
    int base = bin << 9;
    for (int l = t; l < 512; l += 256) {
        int g = base + l;
        int e = sc[l] - cnt[l];          // exclusive within bucket
        if (g < N) {
            rowBE[g] = make_int2(b0 + e, b0 + sc[l]);
            norm_in[g] = rsqrtf(fmaxf((float)cnt[l], 1.0f));
        }
        cnt[l] = e;                      // becomes placement cursor
    }
    __syncthreads();
    for (int j = t; j < cn; j += 256) {
        int p = bucketD[b0 + j];
        int sv = p >> 9, dl = p & 511;
        int pos = atomicAdd(&cnt[dl], 1);
        edges[b0 + pos] = make_int2(sv, __float_as_int(norm_out[sv]));
    }
}

// shared gather primitive: sum_e w_e * h4[src_e*G + lane], 8-edge unroll
template <int G>
__device__ __forceinline__ float4 gather_row(const float4* __restrict__ h4,
                                             const int2* __restrict__ edges,
                                             int j, int end, int lane) {
    float4 acc = make_float4(0.f, 0.f, 0.f, 0.f);
    for (; j + 7 < end; j += 8) {
        int2 e[8];
        float4 v[8];
#pragma unroll
        for (int q = 0; q < 8; q++) e[q] = edges[j + q];
#pragma unroll
        for (int q = 0; q < 8; q++) v[q] = h4[(size_t)e[q].x * G + lane];
#pragma unroll
        for (int q = 0; q < 8; q++) {
            float wq = __int_as_float(e[q].y);
            acc.x += v[q].x * wq; acc.y += v[q].y * wq;
            acc.z += v[q].z * wq; acc.w += v[q].w * wq;
        }
    }
    if (j + 3 < end) {
        int2 e0 = edges[j], e1 = edges[j + 1], e2 = edges[j + 2], e3 = edges[j + 3];
        float4 v0 = h4[(size_t)e0.x * G + lane];
        float4 v1 = h4[(size_t)e1.x * G + lane];
        float4 v2 = h4[(size_t)e2.x * G + lane];
        float4 v3 = h4[(size_t)e3.x * G + lane];
        float w0 = __int_as_float(e0.y), w1 = __int_as_float(e1.y);
        float w2 = __int_as_float(e2.y), w3 = __int_as_float(e3.y);
        acc.x += v0.x * w0 + v1.x * w1 + v2.x * w2 + v3.x * w3;
        acc.y += v0.y * w0 + v1.y * w1 + v2.y * w2 + v3.y * w3;
        acc.z += v0.z * w0 + v1.z * w1 + v2.z * w2 + v3.z * w3;
        acc.w += v0.w * w0 + v1.w * w1 + v2.w * w2 + v3.w * w3;
        j += 4;
    }
    for (; j < end; j++) {
        int2 e = edges[j];
        float4 v = h4[(size_t)e.x * G + lane];
        float w0 = __int_as_float(e.y);
        acc.x += v.x * w0; acc.y += v.y * w0; acc.z += v.z * w0; acc.w += v.w * w0;
    }
    return acc;
}

// --- L1+L2 fused, W streamed in 8KB chunks (R13): per 32-row block:
//   A = agg(x)*norm_in  (gather -> LDS)
//   H = relu(A@W1 + b1) (regs -> LDS)
//   t2 = H@W2           (-> global)
// LDS = A 16.9KB + Wchunk 8KB = 24.9KB -> 6 blocks/CU.
__global__ __launch_bounds__(256) void k_fused1(const float4* __restrict__ x4,
                        const int2* __restrict__ edges, const int2* __restrict__ rowBE,
                        const float* __restrict__ norm, const float* __restrict__ W1,
                        const float* __restrict__ b1, const float* __restrict__ W2,
                        int N, float* __restrict__ t2) {
    constexpr int AP = 33;                 // float4 slots per k4; AP%8==1 -> free staging
    __shared__ float4 Alds[32 * AP];       // phase1: [k4<16][r<32] ; phase2: [k4<32][r<32]
    __shared__ float  Wlds[2048];          // 8KB W chunk
    int t = threadIdx.x;
    int row0 = blockIdx.x * 32;
    // gather phase: 2 passes x (16 nodes x 16 float4-lanes)
#pragma unroll
    for (int pass = 0; pass < 2; pass++) {
        int r = pass * 16 + (t >> 4);
        int lane = t & 15;
        int node = row0 + r;
        float4 acc = make_float4(0.f, 0.f, 0.f, 0.f);
        if (node < N) {
            int2 be = rowBE[node];
            acc = gather_row<16>(x4, edges, be.x, be.y, lane);
            float s = norm[node];
            acc.x *= s; acc.y *= s; acc.z *= s; acc.w *= s;
        }
        Alds[lane * AP + r] = acc;
    }
    // GEMM1: 32x64 @ 64x128, 4x4/thread (tx<32, ty<8); W1 in 4 chunks of 16 k-rows
    int tx = t & 31, ty = t >> 5;
    float acc1[4][4] = {};
#pragma unroll
    for (int c = 0; c < 4; c++) {
        // stage W1 rows [c*16, c*16+16) = 2048 floats
        ((float4*)Wlds)[t]       = ((const float4*)(W1 + c * 16 * 128))[t];
        ((float4*)Wlds)[t + 256] = ((const float4*)(W1 + c * 16 * 128))[t + 256];
        __syncthreads();
#pragma unroll
        for (int k4l = 0; k4l < 4; k4l++) {
            int k4 = c * 4 + k4l;
            float4 a0 = Alds[k4 * AP + ty * 4 + 0];
            float4 a1 = Alds[k4 * AP + ty * 4 + 1];
            float4 a2 = Alds[k4 * AP + ty * 4 + 2];
            float4 a3 = Alds[k4 * AP + ty * 4 + 3];
            const float* wb = &Wlds[(k4l * 4) * 128 + tx * 4];
            float4 w0 = *(const float4*)(wb);
            float4 w1 = *(const float4*)(wb + 128);
            float4 w2 = *(const float4*)(wb + 256);
            float4 w3 = *(const float4*)(wb + 384);
#define GSTEP(AK, WV) \
            acc1[0][0] += a0.AK * WV.x; acc1[0][1] += a0.AK * WV.y; acc1[0][2] += a0.AK * WV.z; acc1[0][3] += a0.AK * WV.w; \
            acc1[1][0] += a1.AK * WV.x; acc1[1][1] += a1.AK * WV.y; acc1[1][2] += a1.AK * WV.z; acc1[1][3] += a1.AK * WV.w; \
            acc1[2][0] += a2.AK * WV.x; acc1[2][1] += a2.AK * WV.y; acc1[2][2] += a2.AK * WV.z; acc1[2][3] += a2.AK * WV.w; \
            acc1[3][0] += a3.AK * WV.x; acc1[3][1] += a3.AK * WV.y; acc1[3][2] += a3.AK * WV.z; acc1[3][3] += a3.AK * WV.w;
            GSTEP(x, w0) GSTEP(y, w1) GSTEP(z, w2) GSTEP(w, w3)
        }
        __syncthreads();
    }
    float4 bb = *(const float4*)(b1 + tx * 4);
    float4 h[4];
#pragma unroll
    for (int i = 0; i < 4; i++) {
        h[i].x = fmaxf(acc1[i][0] + bb.x, 0.f);
        h[i].y = fmaxf(acc1[i][1] + bb.y, 0.f);
        h[i].z = fmaxf(acc1[i][2] + bb.z, 0.f);
        h[i].w = fmaxf(acc1[i][3] + bb.w, 0.f);
    }
    // last GEMM1 sync done above -> safe to overwrite Alds with H: [k4=tx][r]
#pragma unroll
    for (int i = 0; i < 4; i++) Alds[tx * AP + ty * 4 + i] = h[i];
    // GEMM2: 32x128 @ 128x64, 2x4/thread (tx2<16, ty2<16); W2 in 4 chunks of 32 k-rows
    int tx2 = t & 15, ty2 = t >> 4;
    float acc2[2][4] = {};
#pragma unroll
    for (int c = 0; c < 4; c++) {
        ((float4*)Wlds)[t]       = ((const float4*)(W2 + c * 32 * 64))[t];
        ((float4*)Wlds)[t + 256] = ((const float4*)(W2 + c * 32 * 64))[t + 256];
        __syncthreads();
#pragma unroll
        for (int k4l = 0; k4l < 8; k4l++) {
            int k4 = c * 8 + k4l;
            float4 a0 = Alds[k4 * AP + ty2 * 2 + 0];
            float4 a1 = Alds[k4 * AP + ty2 * 2 + 1];
            const float* wb = &Wlds[(k4l * 4) * 64 + tx2 * 4];
            float4 w0 = *(const float4*)(wb);
            float4 w1 = *(const float4*)(wb + 64);
            float4 w2 = *(const float4*)(wb + 128);
            float4 w3 = *(const float4*)(wb + 192);
#define GSTEP2(AK, WV) \
            acc2[0][0] += a0.AK * WV.x; acc2[0][1] += a0.AK * WV.y; acc2[0][2] += a0.AK * WV.z; acc2[0][3] += a0.AK * WV.w; \
            acc2[1][0] += a1.AK * WV.x; acc2[1][1] += a1.AK * WV.y; acc2[1][2] += a1.AK * WV.z; acc2[1][3] += a1.AK * WV.w;
            GSTEP2(x, w0) GSTEP2(y, w1) GSTEP2(z, w2) GSTEP2(w, w3)
#undef GSTEP2
        }
        __syncthreads();
    }
#pragma unroll
    for (int i = 0; i < 2; i++) {
        int grow = row0 + ty2 * 2 + i;
        if (grow < N) {
            float4 o = make_float4(acc2[i][0], acc2[i][1], acc2[i][2], acc2[i][3]);
            *(float4*)(t2 + (size_t)grow * 64 + tx2 * 4) = o;
        }
    }
#undef GSTEP
}

// --- L2-agg + L3 fused: per 32-row block:
//   H2 = relu(agg(t2)*norm + b2)  (gather -> LDS)
//   t3 = H2@W3                    (-> global)
__global__ __launch_bounds__(256) void k_fused2(const float4* __restrict__ t2_4,
                        const int2* __restrict__ edges, const int2* __restrict__ rowBE,
                        const float* __restrict__ norm, const float* __restrict__ b2,
                        const float* __restrict__ W3, int N, float* __restrict__ t3) {
    constexpr int AP = 33;
    __shared__ float4 Alds[16 * AP];       // [k4<16][r<32]
    __shared__ float  Wlds[64 * 32];       // W3
    int t = threadIdx.x;
    int row0 = blockIdx.x * 32;
#pragma unroll
    for (int pass = 0; pass < 2; pass++) {
        int r = pass * 16 + (t >> 4);
        int lane = t & 15;
        int node = row0 + r;
        float4 acc = make_float4(0.f, 0.f, 0.f, 0.f);
        if (node < N) {
            int2 be = rowBE[node];
            acc = gather_row<16>(t2_4, edges, be.x, be.y, lane);
            float s = norm[node];
            float4 b = ((const float4*)b2)[lane];
            acc.x = fmaxf(acc.x * s + b.x, 0.f);
            acc.y = fmaxf(acc.y * s + b.y, 0.f);
            acc.z = fmaxf(acc.z * s + b.z, 0.f);
            acc.w = fmaxf(acc.w * s + b.w, 0.f);
        }
        Alds[lane * AP + r] = acc;
    }
    for (int idx = t; idx < 64 * 32 / 4; idx += 256)
        ((float4*)Wlds)[idx] = ((const float4*)W3)[idx];
    __syncthreads();
    // GEMM3: 32x64 @ 64x32, 1 row x 4 cols/thread (tx<8, ty<32)
    int tx = t & 7, ty = t >> 3;
    float acc3[4] = {};
#pragma unroll 2
    for (int k4 = 0; k4 < 16; k4++) {
        float4 a = Alds[k4 * AP + ty];
        const float* wb = &Wlds[(k4 * 4) * 32 + tx * 4];
        float4 w0 = *(const float4*)(wb);
        float4 w1 = *(const float4*)(wb + 32);
        float4 w2 = *(const float4*)(wb + 64);
        float4 w3 = *(const float4*)(wb + 96);
        acc3[0] += a.x * w0.x + a.y * w1.x + a.z * w2.x + a.w * w3.x;
        acc3[1] += a.x * w0.y + a.y * w1.y + a.z * w2.y + a.w * w3.y;
        acc3[2] += a.x * w0.z + a.y * w1.z + a.z * w2.z + a.w * w3.z;
        acc3[3] += a.x * w0.w + a.y * w1.w + a.z * w2.w + a.w * w3.w;
    }
    int grow = row0 + ty;
    if (grow < N) {
        float4 o = make_float4(acc3[0], acc3[1], acc3[2], acc3[3]);
        *(float4*)(t3 + (size_t)grow * 32 + tx * 4) = o;
    }
}

// agg3 + W4 fused (D=32): h3 = relu(agg(t3)*norm+b3) in regs (never stored),
// t4[node] = h3 @ W4 via per-lane partials + 8-lane __shfl_xor reduce.
__global__ __launch_bounds__(256) void k_aggw4(const float4* __restrict__ h4,
                        const int2* __restrict__ edges, const int2* __restrict__ rowBE,
                        const float* __restrict__ norm, const float4* __restrict__ b3_4,
                        const float* __restrict__ W4, int n, float4* __restrict__ t4) {
    __shared__ float w[128];
    if (threadIdx.x < 128) w[threadIdx.x] = W4[threadIdx.x];
    __syncthreads();
    int node = blockIdx.x * 32 + threadIdx.x / 8;
    int lane = threadIdx.x % 8;
    if (node >= n) return;
    float4 wr0 = ((const float4*)w)[4 * lane + 0];
    float4 wr1 = ((const float4*)w)[4 * lane + 1];
    float4 wr2 = ((const float4*)w)[4 * lane + 2];
    float4 wr3 = ((const float4*)w)[4 * lane + 3];
    int2 be = rowBE[node];
    float4 acc = gather_row<8>(h4, edges, be.x, be.y, lane);
    float s = norm[node];
    float4 b = b3_4[lane];
    float hx = fmaxf(acc.x * s + b.x, 0.f);
    float hy = fmaxf(acc.y * s + b.y, 0.f);
    float hz = fmaxf(acc.z * s + b.z, 0.f);
    float hw = fmaxf(acc.w * s + b.w, 0.f);
    float4 p;
    p.x = hx * wr0.x + hy * wr1.x + hz * wr2.x + hw * wr3.x;
    p.y = hx * wr0.y + hy * wr1.y + hz * wr2.y + hw * wr3.y;
    p.z = hx * wr0.z + hy * wr1.z + hz * wr2.z + hw * wr3.z;
    p.w = hx * wr0.w + hy * wr1.w + hz * wr2.w + hw * wr3.w;
#pragma unroll
    for (int m = 1; m < 8; m <<= 1) {
        p.x += __shfl_xor(p.x, m);
        p.y += __shfl_xor(p.y, m);
        p.z += __shfl_xor(p.z, m);
        p.w += __shfl_xor(p.w, m);
    }
    if (lane == 0) t4[node] = p;
}

// L4 fused: per node (1 thread): acc = sum_e t4[src_e]*w_e ; v = acc*norm+b4 ;
// wave segmented-scan pool on sorted gid -> atomics
__global__ __launch_bounds__(256) void k_aggpool(const float4* __restrict__ t4,
                        const int2* __restrict__ edges, const int2* __restrict__ rowBE,
                        const float* __restrict__ norm, const float* __restrict__ b4,
                        const int* __restrict__ gid, int N,
                        float* __restrict__ sums, float* __restrict__ counts) {
    int n = blockIdx.x * blockDim.x + threadIdx.x;
    int lane = threadIdx.x & 63;
    bool valid = (n < N);
    float v0 = 0.f, v1 = 0.f, v2 = 0.f, v3 = 0.f, cnt = 0.f;
    int g = -1;
    if (valid) {
        g = gid[n];
        int2 be = rowBE[n];
        float4 acc = gather_row<1>(t4, edges, be.x, be.y, 0);
        float s = norm[n];
        v0 = acc.x * s + b4[0];
        v1 = acc.y * s + b4[1];
        v2 = acc.z * s + b4[2];
        v3 = acc.w * s + b4[3];
        cnt = 1.f;
    }
#pragma unroll
    for (int off = 1; off < 64; off <<= 1) {
        float u0 = __shfl_up(v0, off);
        float u1 = __shfl_up(v1, off);
        float u2 = __shfl_up(v2, off);
        float u3 = __shfl_up(v3, off);
        float uc = __shfl_up(cnt, off);
        int   ug = __shfl_up(g, off);
        if (lane >= off && ug == g) { v0 += u0; v1 += u1; v2 += u2; v3 += u3; cnt += uc; }
    }
    int gnext = __shfl_down(g, 1);
    bool boundary = (lane == 63) || (gnext != g);
    if (boundary && valid) {
        atomicAdd(&sums[g * 4 + 0], v0);
        atomicAdd(&sums[g * 4 + 1], v1);
        atomicAdd(&sums[g * 4 + 2], v2);
        atomicAdd(&sums[g * 4 + 3], v3);
        atomicAdd(&counts[g], cnt);
    }
}

__global__ void k_div(const float* __restrict__ sums, const float* __restrict__ counts,
                      int G, float* __restrict__ out) {
    int idx = blockIdx.x * blockDim.x + threadIdx.x;
    if (idx >= G * 4) return;
    out[idx] = sums[idx] / fmaxf(counts[idx >> 2], 1.0f);
}

extern "C" void kernel_launch(void* const* d_in, const int* in_sizes, int n_in,
                              void* d_out, int out_size, void* d_ws, size_t ws_size,
                              hipStream_t stream) {
    const float* x  = (const float*)d_in[0];
    const float* W1 = (const float*)d_in[1];
    const float* b1 = (const float*)d_in[2];
    const float* W2 = (const float*)d_in[3];
    const float* b2 = (const float*)d_in[4];
    const float* W3 = (const float*)d_in[5];
    const float* b3 = (const float*)d_in[6];
    const float* W4 = (const float*)d_in[7];
    const float* b4 = (const float*)d_in[8];
    const int* src = (const int*)d_in[9];
    const int* dst = (const int*)d_in[10];
    const int* gid = (const int*)d_in[11];

    const int N = in_sizes[0] / 64;
    const int E = in_sizes[9];
    const int G = out_size / 4;
    const int NP = ((N + 63) / 64) * 64;
    const int NBIN = (N + 511) >> 9;          // coarse bins (<=256 for N<=131072)
    const int T = (E + TILE - 1) / TILE;      // build tiles

    char* ws = (char*)d_ws;
    size_t off = 0;
    auto alloc = [&](size_t bytes) -> void* {
        void* p = (void*)(ws + off);
        off += (bytes + 255) & ~(size_t)255;
        return p;
    };
    float* sums     = (float*)alloc(2048 * 4);   // 500*4 used
    float* counts   = (float*)alloc(512 * 4);
    int*   cntD     = (int*)alloc(256 * 4);
    int*   cntS     = (int*)alloc(256 * 4);
    int*   bucketD  = (int*)alloc((size_t)NBIN * SLOT * 4);
    unsigned short* bucketS = (unsigned short*)alloc((size_t)NBIN * SLOT * 2);
    int2*  edges    = (int2*)alloc((size_t)NBIN * SLOT * 8);
    int2*  rowBE    = (int2*)alloc((size_t)NP * 8);
    float* norm_out = (float*)alloc((size_t)NP * 4);
    float* norm_in  = (float*)alloc((size_t)NP * 4);
    float* t2buf    = (float*)alloc((size_t)N * 64 * 4);
    float* t3buf    = (float*)alloc((size_t)N * 32 * 4);
    float* t4buf    = (float*)alloc((size_t)N * 4 * 4);

    hipMemsetAsync(sums, 0, (2048 + 512 + 256 + 256) * 4, stream);

    // ---- slotted atomic-light CSR build (3 kernels) ----
    k_buildbins<<<T, 256, 0, stream>>>(src, dst, E, NBIN, cntD, cntS, bucketD, bucketS);
    k_degout<<<NBIN, 256, 0, stream>>>(bucketS, cntS, N, norm_out);
    k_build<<<NBIN, 256, 0, stream>>>(bucketD, cntD, norm_out, N, rowBE, norm_in, edges);

    int fb = (N + 31) / 32;
    int nb = (N + 255) / 256;
    // L1+L2: t2 = relu(agg(x)*norm@W1+b1)@W2
    k_fused1<<<fb, 256, 0, stream>>>((const float4*)x, edges, rowBE, norm_in,
                                     W1, b1, W2, N, t2buf);
    // L2-agg+L3: t3 = relu(agg(t2)*norm+b2)@W3
    k_fused2<<<fb, 256, 0, stream>>>((const float4*)t2buf, edges, rowBE, norm_in,
                                     b2, W3, N, t3buf);
    // L3-agg+L4-W: t4 = relu(agg(t3)*norm+b3)@W4
    k_aggw4<<<fb, 256, 0, stream>>>((const float4*)t3buf, edges, rowBE,
                                    norm_in, (const float4*)b3, W4, N,
                                    (float4*)t4buf);
    // L4: fused gather(t4)+norm+bias+pool
    k_aggpool<<<nb, 256, 0, stream>>>((const float4*)t4buf, edges, rowBE,
                                      norm_in, b4, gid, N, sums, counts);
    k_div<<<(G * 4 + 255) / 256, 256, 0, stream>>>(sums, counts, G, (float*)d_out);
}

// Round 14
// 270.472 us; speedup vs baseline: 3.2585x; 3.2585x over previous
//
#include <hip/hip_runtime.h>
#include <hip/hip_bf16.h>

// ---------------------------------------------------------------------------
// GCN 4-layer forward on MI355X.
//   - R6: single-pass SLOTTED CSR build (one device atomic per (bin,tile)).
//   - R5/R7: float4 gathers, 8-edge unroll.
//   - R10/R11: LDS bank law: dense float4 @16B*tid stride and stride AP%8==1
//     staging are free; transposed scalar staging (stride==4 mod 32) is 8-way.
//   - R12: mega-fusion (agg+GEMM1+GEMM2 in one kernel; h1/agg1/h2 never HBM).
//   - R13 FAILURE: W-chunking with unrolled chunk loops -> compiler pipelined
//     global W-loads across barriers -> 256 VGPR + 1.8GB scratch spill ->
//     708us. R14 fix: '#pragma unroll 1' pins the chunk loops as real loops;
//     LDS stays 24.9KB (6 blocks/CU) without the register explosion.
//   - pool: wave segmented scan on sorted gid (R1: contended atomics 152us).
// ---------------------------------------------------------------------------

#define TILE 4096   // edges per build tile (256 threads x 16)
#define SLOT 8192   // per-bin slot capacity (bin = 512 nodes, mean ~4080 edges)

// --- build pass 1: tile->LDS, histogram, reserve slot space, scatter -------
__global__ __launch_bounds__(256) void k_buildbins(
        const int* __restrict__ src, const int* __restrict__ dst, int E, int NBIN,
        int* __restrict__ cntD, int* __restrict__ cntS,
        int* __restrict__ bucketD, unsigned short* __restrict__ bucketS) {
    __shared__ int ssrc[TILE];
    __shared__ int sdst[TILE];
    __shared__ int hD[256], hS[256], bD[256], bS[256];
    int t = threadIdx.x;
    hD[t] = 0; hS[t] = 0;
    __syncthreads();
    int base = blockIdx.x * TILE;
    int lim = min(TILE, E - base);
#pragma unroll
    for (int k = 0; k < TILE / 256; k++) {
        int i = k * 256 + t;
        if (i < lim) {
            int d = dst[base + i], sv = src[base + i];
            sdst[i] = d; ssrc[i] = sv;
            atomicAdd(&hD[d >> 9], 1);
            atomicAdd(&hS[sv >> 9], 1);
        }
    }
    __syncthreads();
    if (t < NBIN) {
        bD[t] = (hD[t] > 0) ? atomicAdd(&cntD[t], hD[t]) : 0;
        bS[t] = (hS[t] > 0) ? atomicAdd(&cntS[t], hS[t]) : 0;
        hD[t] = 0; hS[t] = 0;
    }
    __syncthreads();
#pragma unroll
    for (int k = 0; k < TILE / 256; k++) {
        int i = k * 256 + t;
        if (i < lim) {
            int d = sdst[i], sv = ssrc[i];
            int binD = d >> 9, binS = sv >> 9;
            int pD = atomicAdd(&hD[binD], 1) + bD[binD];
            bucketD[binD * SLOT + pD] = (sv << 9) | (d & 511);
            int pS = atomicAdd(&hS[binS], 1) + bS[binS];
            bucketS[binS * SLOT + pS] = (unsigned short)(sv & 511);
        }
    }
}

// --- build pass 2: per-src-bucket LDS count -> norm_out --------------------
__global__ __launch_bounds__(256) void k_degout(const unsigned short* __restrict__ bucketS,
                                                const int* __restrict__ cntS,
                                                int N, float* __restrict__ norm_out) {
    __shared__ int cnt[512];
    int t = threadIdx.x;
    cnt[t] = 0; cnt[t + 256] = 0;
    __syncthreads();
    int bin = blockIdx.x;
    int b0 = bin * SLOT, cn = cntS[bin];
    for (int j = t; j < cn; j += 256) atomicAdd(&cnt[bucketS[b0 + j]], 1);
    __syncthreads();
    int base = bin << 9;
    for (int l = t; l < 512; l += 256) {
        int g = base + l;
        if (g < N) norm_out[g] = rsqrtf(fmaxf((float)cnt[l], 1.0f));
    }
}

// --- build pass 3: per-dst-bucket count+scan -> rowBE/norm_in, place edges -
__global__ __launch_bounds__(256) void k_build(const int* __restrict__ bucketD,
                                               const int* __restrict__ cntDg,
                                               const float* __restrict__ norm_out,
                                               int N, int2* __restrict__ rowBE,
                                               float* __restrict__ norm_in,
                                               int2* __restrict__ edges) {
    __shared__ int cnt[512], sc[512];
    int t = threadIdx.x;
    cnt[t] = 0; cnt[t + 256] = 0;
    __syncthreads();
    int bin = blockIdx.x;
    int b0 = bin * SLOT, cn = cntDg[bin];
    for (int j = t; j < cn; j += 256) atomicAdd(&cnt[bucketD[b0 + j] & 511], 1);
    __syncthreads();
    sc[t] = cnt[t]; sc[t + 256] = cnt[t + 256];
    __syncthreads();
    for (int off = 1; off < 512; off <<= 1) {
        int v0 = (t >= off) ? sc[t - off] : 0;
        int i1 = t + 256;
        int v1 = sc[i1 - off];   // i1 >= 256 >= off always
        __syncthreads();
        sc[t] += v0; sc[i1] += v1;
        __syncthreads();
    }
    int base = bin << 9;
    for (int l = t; l < 512; l += 256) {
        int g = base + l;
        int e = sc[l] - cnt[l];          // exclusive within bucket
        if (g < N) {
            rowBE[g] = make_int2(b0 + e, b0 + sc[l]);
            norm_in[g] = rsqrtf(fmaxf((float)cnt[l], 1.0f));
        }
        cnt[l] = e;                      // becomes placement cursor
    }
    __syncthreads();
    for (int j = t; j < cn; j += 256) {
        int p = bucketD[b0 + j];
        int sv = p >> 9, dl = p & 511;
        int pos = atomicAdd(&cnt[dl], 1);
        edges[b0 + pos] = make_int2(sv, __float_as_int(norm_out[sv]));
    }
}

// shared gather primitive: sum_e w_e * h4[src_e*G + lane], 8-edge unroll
template <int G>
__device__ __forceinline__ float4 gather_row(const float4* __restrict__ h4,
                                             const int2* __restrict__ edges,
                                             int j, int end, int lane) {
    float4 acc = make_float4(0.f, 0.f, 0.f, 0.f);
    for (; j + 7 < end; j += 8) {
        int2 e[8];
        float4 v[8];
#pragma unroll
        for (int q = 0; q < 8; q++) e[q] = edges[j + q];
#pragma unroll
        for (int q = 0; q < 8; q++) v[q] = h4[(size_t)e[q].x * G + lane];
#pragma unroll
        for (int q = 0; q < 8; q++) {
            float wq = __int_as_float(e[q].y);
            acc.x += v[q].x * wq; acc.y += v[q].y * wq;
            acc.z += v[q].z * wq; acc.w += v[q].w * wq;
        }
    }
    if (j + 3 < end) {
        int2 e0 = edges[j], e1 = edges[j + 1], e2 = edges[j + 2], e3 = edges[j + 3];
        float4 v0 = h4[(size_t)e0.x * G + lane];
        float4 v1 = h4[(size_t)e1.x * G + lane];
        float4 v2 = h4[(size_t)e2.x * G + lane];
        float4 v3 = h4[(size_t)e3.x * G + lane];
        float w0 = __int_as_float(e0.y), w1 = __int_as_float(e1.y);
        float w2 = __int_as_float(e2.y), w3 = __int_as_float(e3.y);
        acc.x += v0.x * w0 + v1.x * w1 + v2.x * w2 + v3.x * w3;
        acc.y += v0.y * w0 + v1.y * w1 + v2.y * w2 + v3.y * w3;
        acc.z += v0.z * w0 + v1.z * w1 + v2.z * w2 + v3.z * w3;
        acc.w += v0.w * w0 + v1.w * w1 + v2.w * w2 + v3.w * w3;
        j += 4;
    }
    for (; j < end; j++) {
        int2 e = edges[j];
        float4 v = h4[(size_t)e.x * G + lane];
        float w0 = __int_as_float(e.y);
        acc.x += v.x * w0; acc.y += v.y * w0; acc.z += v.z * w0; acc.w += v.w * w0;
    }
    return acc;
}

// --- L1+L2 fused, W streamed in 8KB chunks; chunk loops pinned with
// '#pragma unroll 1' (R13 failure: unrolled chunks -> 256 VGPR + spills).
// LDS = A 16.9KB + Wchunk 8KB = 24.9KB -> 6 blocks/CU.
__global__ __launch_bounds__(256) void k_fused1(const float4* __restrict__ x4,
                        const int2* __restrict__ edges, const int2* __restrict__ rowBE,
                        const float* __restrict__ norm, const float* __restrict__ W1,
                        const float* __restrict__ b1, const float* __restrict__ W2,
                        int N, float* __restrict__ t2) {
    constexpr int AP = 33;                 // float4 slots per k4; AP%8==1 -> free staging
    __shared__ float4 Alds[32 * AP];       // phase1: [k4<16][r<32] ; phase2: [k4<32][r<32]
    __shared__ float  Wlds[2048];          // 8KB W chunk
    int t = threadIdx.x;
    int row0 = blockIdx.x * 32;
    // gather phase: 2 passes x (16 nodes x 16 float4-lanes)
#pragma unroll
    for (int pass = 0; pass < 2; pass++) {
        int r = pass * 16 + (t >> 4);
        int lane = t & 15;
        int node = row0 + r;
        float4 acc = make_float4(0.f, 0.f, 0.f, 0.f);
        if (node < N) {
            int2 be = rowBE[node];
            acc = gather_row<16>(x4, edges, be.x, be.y, lane);
            float s = norm[node];
            acc.x *= s; acc.y *= s; acc.z *= s; acc.w *= s;
        }
        Alds[lane * AP + r] = acc;
    }
    // GEMM1: 32x64 @ 64x128, 4x4/thread (tx<32, ty<8); W1 in 4 chunks of 16 k-rows
    int tx = t & 31, ty = t >> 5;
    float acc1[4][4] = {};
#pragma unroll 1
    for (int c = 0; c < 4; c++) {
        ((float4*)Wlds)[t]       = ((const float4*)(W1 + c * 16 * 128))[t];
        ((float4*)Wlds)[t + 256] = ((const float4*)(W1 + c * 16 * 128))[t + 256];
        __syncthreads();
#pragma unroll
        for (int k4l = 0; k4l < 4; k4l++) {
            int k4 = c * 4 + k4l;
            float4 a0 = Alds[k4 * AP + ty * 4 + 0];
            float4 a1 = Alds[k4 * AP + ty * 4 + 1];
            float4 a2 = Alds[k4 * AP + ty * 4 + 2];
            float4 a3 = Alds[k4 * AP + ty * 4 + 3];
            const float* wb = &Wlds[(k4l * 4) * 128 + tx * 4];
            float4 w0 = *(const float4*)(wb);
            float4 w1 = *(const float4*)(wb + 128);
            float4 w2 = *(const float4*)(wb + 256);
            float4 w3 = *(const float4*)(wb + 384);
#define GSTEP(AK, WV) \
            acc1[0][0] += a0.AK * WV.x; acc1[0][1] += a0.AK * WV.y; acc1[0][2] += a0.AK * WV.z; acc1[0][3] += a0.AK * WV.w; \
            acc1[1][0] += a1.AK * WV.x; acc1[1][1] += a1.AK * WV.y; acc1[1][2] += a1.AK * WV.z; acc1[1][3] += a1.AK * WV.w; \
            acc1[2][0] += a2.AK * WV.x; acc1[2][1] += a2.AK * WV.y; acc1[2][2] += a2.AK * WV.z; acc1[2][3] += a2.AK * WV.w; \
            acc1[3][0] += a3.AK * WV.x; acc1[3][1] += a3.AK * WV.y; acc1[3][2] += a3.AK * WV.z; acc1[3][3] += a3.AK * WV.w;
            GSTEP(x, w0) GSTEP(y, w1) GSTEP(z, w2) GSTEP(w, w3)
        }
        __syncthreads();
    }
    float4 bb = *(const float4*)(b1 + tx * 4);
    float4 h[4];
#pragma unroll
    for (int i = 0; i < 4; i++) {
        h[i].x = fmaxf(acc1[i][0] + bb.x, 0.f);
        h[i].y = fmaxf(acc1[i][1] + bb.y, 0.f);
        h[i].z = fmaxf(acc1[i][2] + bb.z, 0.f);
        h[i].w = fmaxf(acc1[i][3] + bb.w, 0.f);
    }
    // last GEMM1 sync done above -> safe to overwrite Alds with H: [k4=tx][r]
#pragma unroll
    for (int i = 0; i < 4; i++) Alds[tx * AP + ty * 4 + i] = h[i];
    // GEMM2: 32x128 @ 128x64, 2x4/thread (tx2<16, ty2<16); W2 in 4 chunks of 32 k-rows
    int tx2 = t & 15, ty2 = t >> 4;
    float acc2[2][4] = {};
#pragma unroll 1
    for (int c = 0; c < 4; c++) {
        ((float4*)Wlds)[t]       = ((const float4*)(W2 + c * 32 * 64))[t];
        ((float4*)Wlds)[t + 256] = ((const float4*)(W2 + c * 32 * 64))[t + 256];
        __syncthreads();
#pragma unroll
        for (int k4l = 0; k4l < 8; k4l++) {
            int k4 = c * 8 + k4l;
            float4 a0 = Alds[k4 * AP + ty2 * 2 + 0];
            float4 a1 = Alds[k4 * AP + ty2 * 2 + 1];
            const float* wb = &Wlds[(k4l * 4) * 64 + tx2 * 4];
            float4 w0 = *(const float4*)(wb);
            float4 w1 = *(const float4*)(wb + 64);
            float4 w2 = *(const float4*)(wb + 128);
            float4 w3 = *(const float4*)(wb + 192);
#define GSTEP2(AK, WV) \
            acc2[0][0] += a0.AK * WV.x; acc2[0][1] += a0.AK * WV.y; acc2[0][2] += a0.AK * WV.z; acc2[0][3] += a0.AK * WV.w; \
            acc2[1][0] += a1.AK * WV.x; acc2[1][1] += a1.AK * WV.y; acc2[1][2] += a1.AK * WV.z; acc2[1][3] += a1.AK * WV.w;
            GSTEP2(x, w0) GSTEP2(y, w1) GSTEP2(z, w2) GSTEP2(w, w3)
#undef GSTEP2
        }
        __syncthreads();
    }
#pragma unroll
    for (int i = 0; i < 2; i++) {
        int grow = row0 + ty2 * 2 + i;
        if (grow < N) {
            float4 o = make_float4(acc2[i][0], acc2[i][1], acc2[i][2], acc2[i][3]);
            *(float4*)(t2 + (size_t)grow * 64 + tx2 * 4) = o;
        }
    }
#undef GSTEP
}

// --- L2-agg + L3 fused: per 32-row block:
//   H2 = relu(agg(t2)*norm + b2)  (gather -> LDS)
//   t3 = H2@W3                    (-> global)
__global__ __launch_bounds__(256) void k_fused2(const float4* __restrict__ t2_4,
                        const int2* __restrict__ edges, const int2* __restrict__ rowBE,
                        const float* __restrict__ norm, const float* __restrict__ b2,
                        const float* __restrict__ W3, int N, float* __restrict__ t3) {
    constexpr int AP = 33;
    __shared__ float4 Alds[16 * AP];       // [k4<16][r<32]
    __shared__ float  Wlds[64 * 32];       // W3
    int t = threadIdx.x;
    int row0 = blockIdx.x * 32;
#pragma unroll
    for (int pass = 0; pass < 2; pass++) {
        int r = pass * 16 + (t >> 4);
        int lane = t & 15;
        int node = row0 + r;
        float4 acc = make_float4(0.f, 0.f, 0.f, 0.f);
        if (node < N) {
            int2 be = rowBE[node];
            acc = gather_row<16>(t2_4, edges, be.x, be.y, lane);
            float s = norm[node];
            float4 b = ((const float4*)b2)[lane];
            acc.x = fmaxf(acc.x * s + b.x, 0.f);
            acc.y = fmaxf(acc.y * s + b.y, 0.f);
            acc.z = fmaxf(acc.z * s + b.z, 0.f);
            acc.w = fmaxf(acc.w * s + b.w, 0.f);
        }
        Alds[lane * AP + r] = acc;
    }
    for (int idx = t; idx < 64 * 32 / 4; idx += 256)
        ((float4*)Wlds)[idx] = ((const float4*)W3)[idx];
    __syncthreads();
    // GEMM3: 32x64 @ 64x32, 1 row x 4 cols/thread (tx<8, ty<32)
    int tx = t & 7, ty = t >> 3;
    float acc3[4] = {};
#pragma unroll 2
    for (int k4 = 0; k4 < 16; k4++) {
        float4 a = Alds[k4 * AP + ty];
        const float* wb = &Wlds[(k4 * 4) * 32 + tx * 4];
        float4 w0 = *(const float4*)(wb);
        float4 w1 = *(const float4*)(wb + 32);
        float4 w2 = *(const float4*)(wb + 64);
        float4 w3 = *(const float4*)(wb + 96);
        acc3[0] += a.x * w0.x + a.y * w1.x + a.z * w2.x + a.w * w3.x;
        acc3[1] += a.x * w0.y + a.y * w1.y + a.z * w2.y + a.w * w3.y;
        acc3[2] += a.x * w0.z + a.y * w1.z + a.z * w2.z + a.w * w3.z;
        acc3[3] += a.x * w0.w + a.y * w1.w + a.z * w2.w + a.w * w3.w;
    }
    int grow = row0 + ty;
    if (grow < N) {
        float4 o = make_float4(acc3[0], acc3[1], acc3[2], acc3[3]);
        *(float4*)(t3 + (size_t)grow * 32 + tx * 4) = o;
    }
}

// agg3 + W4 fused (D=32): h3 = relu(agg(t3)*norm+b3) in regs (never stored),
// t4[node] = h3 @ W4 via per-lane partials + 8-lane __shfl_xor reduce.
__global__ __launch_bounds__(256) void k_aggw4(const float4* __restrict__ h4,
                        const int2* __restrict__ edges, const int2* __restrict__ rowBE,
                        const float* __restrict__ norm, const float4* __restrict__ b3_4,
                        const float* __restrict__ W4, int n, float4* __restrict__ t4) {
    __shared__ float w[128];
    if (threadIdx.x < 128) w[threadIdx.x] = W4[threadIdx.x];
    __syncthreads();
    int node = blockIdx.x * 32 + threadIdx.x / 8;
    int lane = threadIdx.x % 8;
    if (node >= n) return;
    float4 wr0 = ((const float4*)w)[4 * lane + 0];
    float4 wr1 = ((const float4*)w)[4 * lane + 1];
    float4 wr2 = ((const float4*)w)[4 * lane + 2];
    float4 wr3 = ((const float4*)w)[4 * lane + 3];
    int2 be = rowBE[node];
    float4 acc = gather_row<8>(h4, edges, be.x, be.y, lane);
    float s = norm[node];
    float4 b = b3_4[lane];
    float hx = fmaxf(acc.x * s + b.x, 0.f);
    float hy = fmaxf(acc.y * s + b.y, 0.f);
    float hz = fmaxf(acc.z * s + b.z, 0.f);
    float hw = fmaxf(acc.w * s + b.w, 0.f);
    float4 p;
    p.x = hx * wr0.x + hy * wr1.x + hz * wr2.x + hw * wr3.x;
    p.y = hx * wr0.y + hy * wr1.y + hz * wr2.y + hw * wr3.y;
    p.z = hx * wr0.z + hy * wr1.z + hz * wr2.z + hw * wr3.z;
    p.w = hx * wr0.w + hy * wr1.w + hz * wr2.w + hw * wr3.w;
#pragma unroll
    for (int m = 1; m < 8; m <<= 1) {
        p.x += __shfl_xor(p.x, m);
        p.y += __shfl_xor(p.y, m);
        p.z += __shfl_xor(p.z, m);
        p.w += __shfl_xor(p.w, m);
    }
    if (lane == 0) t4[node] = p;
}

// L4 fused: per node (1 thread): acc = sum_e t4[src_e]*w_e ; v = acc*norm+b4 ;
// wave segmented-scan pool on sorted gid -> atomics
__global__ __launch_bounds__(256) void k_aggpool(const float4* __restrict__ t4,
                        const int2* __restrict__ edges, const int2* __restrict__ rowBE,
                        const float* __restrict__ norm, const float* __restrict__ b4,
                        const int* __restrict__ gid, int N,
                        float* __restrict__ sums, float* __restrict__ counts) {
    int n = blockIdx.x * blockDim.x + threadIdx.x;
    int lane = threadIdx.x & 63;
    bool valid = (n < N);
    float v0 = 0.f, v1 = 0.f, v2 = 0.f, v3 = 0.f, cnt = 0.f;
    int g = -1;
    if (valid) {
        g = gid[n];
        int2 be = rowBE[n];
        float4 acc = gather_row<1>(t4, edges, be.x, be.y, 0);
        float s = norm[n];
        v0 = acc.x * s + b4[0];
        v1 = acc.y * s + b4[1];
        v2 = acc.z * s + b4[2];
        v3 = acc.w * s + b4[3];
        cnt = 1.f;
    }
#pragma unroll
    for (int off = 1; off < 64; off <<= 1) {
        float u0 = __shfl_up(v0, off);
        float u1 = __shfl_up(v1, off);
        float u2 = __shfl_up(v2, off);
        float u3 = __shfl_up(v3, off);
        float uc = __shfl_up(cnt, off);
        int   ug = __shfl_up(g, off);
        if (lane >= off && ug == g) { v0 += u0; v1 += u1; v2 += u2; v3 += u3; cnt += uc; }
    }
    int gnext = __shfl_down(g, 1);
    bool boundary = (lane == 63) || (gnext != g);
    if (boundary && valid) {
        atomicAdd(&sums[g * 4 + 0], v0);
        atomicAdd(&sums[g * 4 + 1], v1);
        atomicAdd(&sums[g * 4 + 2], v2);
        atomicAdd(&sums[g * 4 + 3], v3);
        atomicAdd(&counts[g], cnt);
    }
}

__global__ void k_div(const float* __restrict__ sums, const float* __restrict__ counts,
                      int G, float* __restrict__ out) {
    int idx = blockIdx.x * blockDim.x + threadIdx.x;
    if (idx >= G * 4) return;
    out[idx] = sums[idx] / fmaxf(counts[idx >> 2], 1.0f);
}

extern "C" void kernel_launch(void* const* d_in, const int* in_sizes, int n_in,
                              void* d_out, int out_size, void* d_ws, size_t ws_size,
                              hipStream_t stream) {
    const float* x  = (const float*)d_in[0];
    const float* W1 = (const float*)d_in[1];
    const float* b1 = (const float*)d_in[2];
    const float* W2 = (const float*)d_in[3];
    const float* b2 = (const float*)d_in[4];
    const float* W3 = (const float*)d_in[5];
    const float* b3 = (const float*)d_in[6];
    const float* W4 = (const float*)d_in[7];
    const float* b4 = (const float*)d_in[8];
    const int* src = (const int*)d_in[9];
    const int* dst = (const int*)d_in[10];
    const int* gid = (const int*)d_in[11];

    const int N = in_sizes[0] / 64;
    const int E = in_sizes[9];
    const int G = out_size / 4;
    const int NP = ((N + 63) / 64) * 64;
    const int NBIN = (N + 511) >> 9;          // coarse bins (<=256 for N<=131072)
    const int T = (E + TILE - 1) / TILE;      // build tiles

    char* ws = (char*)d_ws;
    size_t off = 0;
    auto alloc = [&](size_t bytes) -> void* {
        void* p = (void*)(ws + off);
        off += (bytes + 255) & ~(size_t)255;
        return p;
    };
    float* sums     = (float*)alloc(2048 * 4);   // 500*4 used
    float* counts   = (float*)alloc(512 * 4);
    int*   cntD     = (int*)alloc(256 * 4);
    int*   cntS     = (int*)alloc(256 * 4);
    int*   bucketD  = (int*)alloc((size_t)NBIN * SLOT * 4);
    unsigned short* bucketS = (unsigned short*)alloc((size_t)NBIN * SLOT * 2);
    int2*  edges    = (int2*)alloc((size_t)NBIN * SLOT * 8);
    int2*  rowBE    = (int2*)alloc((size_t)NP * 8);
    float* norm_out = (float*)alloc((size_t)NP * 4);
    float* norm_in  = (float*)alloc((size_t)NP * 4);
    float* t2buf    = (float*)alloc((size_t)N * 64 * 4);
    float* t3buf    = (float*)alloc((size_t)N * 32 * 4);
    float* t4buf    = (float*)alloc((size_t)N * 4 * 4);

    hipMemsetAsync(sums, 0, (2048 + 512 + 256 + 256) * 4, stream);

    // ---- slotted atomic-light CSR build (3 kernels) ----
    k_buildbins<<<T, 256, 0, stream>>>(src, dst, E, NBIN, cntD, cntS, bucketD, bucketS);
    k_degout<<<NBIN, 256, 0, stream>>>(bucketS, cntS, N, norm_out);
    k_build<<<NBIN, 256, 0, stream>>>(bucketD, cntD, norm_out, N, rowBE, norm_in, edges);

    int fb = (N + 31) / 32;
    int nb = (N + 255) / 256;
    // L1+L2: t2 = relu(agg(x)*norm@W1+b1)@W2
    k_fused1<<<fb, 256, 0, stream>>>((const float4*)x, edges, rowBE, norm_in,
                                     W1, b1, W2, N, t2buf);
    // L2-agg+L3: t3 = relu(agg(t2)*norm+b2)@W3
    k_fused2<<<fb, 256, 0, stream>>>((const float4*)t2buf, edges, rowBE, norm_in,
                                     b2, W3, N, t3buf);
    // L3-agg+L4-W: t4 = relu(agg(t3)*norm+b3)@W4
    k_aggw4<<<fb, 256, 0, stream>>>((const float4*)t3buf, edges, rowBE,
                                    norm_in, (const float4*)b3, W4, N,
                                    (float4*)t4buf);
    // L4: fused gather(t4)+norm+bias+pool
    k_aggpool<<<nb, 256, 0, stream>>>((const float4*)t4buf, edges, rowBE,
                                      norm_in, b4, gid, N, sums, counts);
    k_div<<<(G * 4 + 255) / 256, 256, 0, stream>>>(sums, counts, G, (float*)d_out);
}